// Round 7
// baseline (62.944 us; speedup 1.0000x reference)
//
#include <hip/hip_runtime.h>
#include <hip/hip_cooperative_groups.h>
#include <math.h>

namespace cg = cooperative_groups;

#define TPB 256
#define BPB 8                    // batch elements per block
#define CHUNK 256                // rotations staged into LDS per pass
#define NCHUNKS 9                // chunks per block-tile
#define NCHUNK (CHUNK * NCHUNKS) // 2304 rotations per block-tile
#define NTILES 16                // 16 * 2304 = 36864
#define BGRPS 32                 // 256 / BPB
#define LOG2E 1.44269504088896340736f

#if __has_builtin(__builtin_amdgcn_rsqf)
#define FAST_RSQ(x) __builtin_amdgcn_rsqf(x)
#else
#define FAST_RSQ(x) rsqrtf(x)
#endif
#if __has_builtin(__builtin_amdgcn_exp2f)
#define FAST_EXP2(x) __builtin_amdgcn_exp2f(x)
#else
#define FAST_EXP2(x) exp2f(x)
#endif

// {-Z0,-Z4,-Z8,-Z1,-Z2,-Z5, trZ} for FMA-friendly x = trZ - tr(Z R)
__device__ __forceinline__ void compute_Z_neg(const float* __restrict__ L, float zo[7]) {
    float a = L[0], l10 = L[3], c = L[4], d = L[6], e = L[7], f = L[8];
    float ia = 1.0f / a, ic = 1.0f / c, iff = 1.0f / f;
    float m00 = ia;
    float m10 = -l10 * ia * ic;
    float m11 = ic;
    float m20 = (l10 * e - c * d) * ia * ic * iff;
    float m21 = -e * ic * iff;
    float m22 = iff;
    float Z0 = m00*m00 + m10*m10 + m20*m20;
    float Z1 = m10*m11 + m20*m21;
    float Z2 = m20*m22;
    float Z4 = m11*m11 + m21*m21;
    float Z5 = m21*m22;
    float Z8 = m22*m22;
    zo[0] = -Z0; zo[1] = -Z4; zo[2] = -Z8;
    zo[3] = -Z1; zo[4] = -Z2; zo[5] = -Z5;
    zo[6] = Z0 + Z4 + Z8;
}

__device__ __forceinline__ void quat_to_mat(const float q[4], float R[9]) {
    float n = sqrtf(q[0]*q[0] + q[1]*q[1] + q[2]*q[2] + q[3]*q[3]);
    float w = q[0]/n, x = q[1]/n, y = q[2]/n, z = q[3]/n;
    R[0] = 1.f - 2.f*(y*y + z*z);
    R[1] = 2.f*(x*y - w*z);
    R[2] = 2.f*(x*z + w*y);
    R[3] = 2.f*(x*y + w*z);
    R[4] = 1.f - 2.f*(x*x + z*z);
    R[5] = 2.f*(y*z - w*x);
    R[6] = 2.f*(x*z - w*y);
    R[7] = 2.f*(y*z + w*x);
    R[8] = 1.f - 2.f*(x*x + y*y);
}

// partial-sum body: one (tile, bgroup) work item; writes 8 fp64 partials
__device__ __forceinline__ void partial_body(
    int tile, int bg, int tid,
    const float* __restrict__ cov_tril,
    const float* __restrict__ grids,
    double* __restrict__ part, int B,
    float (*zsh)[8], float* gsh, float* red)
{
    if (tid < BPB) {
        float zo[7];
        compute_Z_neg(cov_tril + (bg * BPB + tid) * 9, zo);
#pragma unroll
        for (int j = 0; j < 7; ++j) zsh[tid][j] = zo[j];
    }
    __syncthreads();

    float z[BPB][7];
#pragma unroll
    for (int bl = 0; bl < BPB; ++bl)
#pragma unroll
        for (int j = 0; j < 7; ++j) z[bl][j] = zsh[bl][j];

    float acc[BPB];
#pragma unroll
    for (int bl = 0; bl < BPB; ++bl) acc[bl] = 0.f;

    const float4* gsrc = (const float4*)grids + (size_t)tile * (NCHUNK * 9 / 4);

    for (int c = 0; c < NCHUNKS; ++c) {
        const float4* src = gsrc + c * (CHUNK * 9 / 4);
        float4 v0 = src[tid];
        float4 v1 = src[tid + 256];
        float4 v2;
        if (tid < 64) v2 = src[tid + 512];

        __syncthreads();
        ((float4*)gsh)[tid]       = v0;
        ((float4*)gsh)[tid + 256] = v1;
        if (tid < 64) ((float4*)gsh)[tid + 512] = v2;
        __syncthreads();

        const float* G = gsh + tid * 9;   // stride 9: conflict-free
        float G0=G[0],G1=G[1],G2=G[2],G3=G[3],G4=G[4],G5=G[5],G6=G[6],G7=G[7],G8=G[8];
        float g0 = G0, g1 = G4, g2 = G8;
        float g3 = G1 + G3, g4 = G2 + G6, g5 = G5 + G7;

#pragma unroll
        for (int bl = 0; bl < BPB; ++bl) {
            float x = z[bl][6];
            x = fmaf(z[bl][0], g0, x);
            x = fmaf(z[bl][1], g1, x);
            x = fmaf(z[bl][2], g2, x);
            x = fmaf(z[bl][3], g3, x);
            x = fmaf(z[bl][4], g4, x);
            x = fmaf(z[bl][5], g5, x);
            x = fmaxf(x, 1e-8f);
            float r = FAST_RSQ(x);            // 1/p
            float p = x * r;                  // sqrt(x)
            float e = FAST_EXP2(-LOG2E * p);  // exp(-p)
            acc[bl] = fmaf(e, r, acc[bl]);    // += exp(-p)/p
        }
    }

    // two-stage block reduce: [256 threads][8 b] -> 8 sums
#pragma unroll
    for (int bl = 0; bl < BPB; ++bl) red[tid * 9 + bl] = acc[bl];
    __syncthreads();

    const int bl = tid & 7;
    const int s  = tid >> 3;
    float p_ = 0.f;
#pragma unroll
    for (int j = 0; j < 8; ++j) p_ += red[(s * 8 + j) * 9 + bl];
    __syncthreads();
    red[tid] = p_;
    __syncthreads();

    if (tid < BPB) {
        double S = 0.0;
#pragma unroll
        for (int j = 0; j < 32; ++j) S += (double)red[j * 8 + tid];
        part[(size_t)tile * B + bg * BPB + tid] = S;
    }
}

// finalize body: one b; fixed-order fp64 sum over tiles -> nll
__device__ __forceinline__ void finalize_body(
    int b,
    const float* __restrict__ gt_quat,
    const float* __restrict__ mode_quat,
    const float* __restrict__ cov_tril,
    const double* __restrict__ part,
    float* __restrict__ out, int n_total, int B)
{
    double S = 0.0;
#pragma unroll
    for (int t = 0; t < NTILES; ++t) S += part[(size_t)t * B + b];

    float zo[7];
    compute_Z_neg(cov_tril + b * 9, zo);

    float q0[4] = {mode_quat[b*4+0], mode_quat[b*4+1], mode_quat[b*4+2], mode_quat[b*4+3]};
    float qg[4] = {gt_quat[b*4+0],   gt_quat[b*4+1],   gt_quat[b*4+2],   gt_quat[b*4+3]};
    float R0[9], Rg[9];
    quat_to_mat(q0, R0);
    quat_to_mat(qg, Rg);

    float Rr[9];
#pragma unroll
    for (int i = 0; i < 3; ++i)
#pragma unroll
        for (int j = 0; j < 3; ++j)
            Rr[i*3+j] = R0[0*3+i]*Rg[0*3+j] + R0[1*3+i]*Rg[1*3+j] + R0[2*3+i]*Rg[2*3+j];

    float x = zo[6];
    x = fmaf(zo[0], Rr[0], x);
    x = fmaf(zo[1], Rr[4], x);
    x = fmaf(zo[2], Rr[8], x);
    x = fmaf(zo[3], Rr[1] + Rr[3], x);
    x = fmaf(zo[4], Rr[2] + Rr[6], x);
    x = fmaf(zo[5], Rr[5] + Rr[7], x);

    float power = sqrtf(fmaxf(x, 1e-8f));
    float logF  = (float)(log(S) - log((double)n_total));
    out[b] = logF + power + logf(power);
}

// ---- cooperative single-node kernel
__global__ __launch_bounds__(TPB) void k_coop(
    const float* __restrict__ gt_quat,
    const float* __restrict__ mode_quat,
    const float* __restrict__ cov_tril,
    const float* __restrict__ grids,
    double* __restrict__ part,
    float* __restrict__ out, int n_total, int B)
{
    __shared__ float zsh[BPB][8];
    __shared__ float gsh[CHUNK * 9];
    __shared__ float red[TPB * 9];

    partial_body(blockIdx.x, blockIdx.y, threadIdx.x, cov_tril, grids, part, B,
                 zsh, gsh, red);

    cg::this_grid().sync();

    if (blockIdx.x == 0 && blockIdx.y == 0)
        finalize_body(threadIdx.x, gt_quat, mode_quat, cov_tril, part, out, n_total, B);
}

// ---- fallback pair (identical math, two nodes)
__global__ __launch_bounds__(TPB) void k_part(
    const float* __restrict__ cov_tril,
    const float* __restrict__ grids,
    double* __restrict__ part, int B)
{
    __shared__ float zsh[BPB][8];
    __shared__ float gsh[CHUNK * 9];
    __shared__ float red[TPB * 9];
    partial_body(blockIdx.x, blockIdx.y, threadIdx.x, cov_tril, grids, part, B,
                 zsh, gsh, red);
}

__global__ __launch_bounds__(TPB) void k_fin(
    const float* __restrict__ gt_quat,
    const float* __restrict__ mode_quat,
    const float* __restrict__ cov_tril,
    const double* __restrict__ part,
    float* __restrict__ out, int n_total, int B)
{
    finalize_body(threadIdx.x, gt_quat, mode_quat, cov_tril, part, out, n_total, B);
}

extern "C" void kernel_launch(void* const* d_in, const int* in_sizes, int n_in,
                              void* d_out, int out_size, void* d_ws, size_t ws_size,
                              hipStream_t stream) {
    const float* gt    = (const float*)d_in[0];
    const float* mode  = (const float*)d_in[1];
    const float* cov   = (const float*)d_in[2];
    const float* grids = (const float*)d_in[3];
    float* out = (float*)d_out;

    int B       = in_sizes[0] / 4;     // 256
    int n_total = in_sizes[3] / 9;     // 36864

    double* part = (double*)d_ws;      // 16*256 doubles = 32 KB

    void* args[] = {(void*)&gt, (void*)&mode, (void*)&cov, (void*)&grids,
                    (void*)&part, (void*)&out, (void*)&n_total, (void*)&B};
    dim3 grid(NTILES, BGRPS);          // 512 blocks = 2/CU (ample coop headroom)
    dim3 block(TPB);

    hipError_t err = hipLaunchCooperativeKernel((const void*)k_coop, grid, block,
                                                args, 0, stream);
    if (err != hipSuccess) {
        (void)hipGetLastError();       // clear sticky error, then fallback (2 nodes)
        k_part<<<grid, block, 0, stream>>>(cov, grids, part, B);
        k_fin<<<1, block, 0, stream>>>(gt, mode, cov, part, out, n_total, B);
    }
}

// Round 8
// 36.525 us; speedup vs baseline: 1.7233x; 1.7233x over previous
//
#include <hip/hip_runtime.h>
#include <math.h>

#define TPB 256
#define BPB 8                    // batch elements per block
#define CHUNK 256                // rotations staged into LDS per pass
#define NCHUNKS 6                // chunks per block-tile
#define NCHUNK (CHUNK * NCHUNKS) // 1536 rotations per block-tile
#define NTILES 24                // 24 * 1536 = 36864
#define BGRPS 32                 // 256 / BPB
#define NBLOCKS (NTILES * BGRPS) // 768
#define LOG2E 1.44269504088896340736f

#if __has_builtin(__builtin_amdgcn_rsqf)
#define FAST_RSQ(x) __builtin_amdgcn_rsqf(x)
#else
#define FAST_RSQ(x) rsqrtf(x)
#endif
#if __has_builtin(__builtin_amdgcn_exp2f)
#define FAST_EXP2(x) __builtin_amdgcn_exp2f(x)
#else
#define FAST_EXP2(x) exp2f(x)
#endif

// Completion counter. NOT in d_ws (harness poisons d_ws to 0xAA). Zero at module
// load; the finalizing block restores it to 0 at the end of EVERY launch, so each
// call observes identical initial state -> deterministic, no memset node needed.
__device__ unsigned g_cnt = 0;

// {-Z0,-Z4,-Z8,-Z1,-Z2,-Z5, trZ} for FMA-friendly x = trZ - tr(Z R)
__device__ __forceinline__ void compute_Z_neg(const float* __restrict__ L, float zo[7]) {
    float a = L[0], l10 = L[3], c = L[4], d = L[6], e = L[7], f = L[8];
    float ia = 1.0f / a, ic = 1.0f / c, iff = 1.0f / f;
    float m00 = ia;
    float m10 = -l10 * ia * ic;
    float m11 = ic;
    float m20 = (l10 * e - c * d) * ia * ic * iff;
    float m21 = -e * ic * iff;
    float m22 = iff;
    float Z0 = m00*m00 + m10*m10 + m20*m20;
    float Z1 = m10*m11 + m20*m21;
    float Z2 = m20*m22;
    float Z4 = m11*m11 + m21*m21;
    float Z5 = m21*m22;
    float Z8 = m22*m22;
    zo[0] = -Z0; zo[1] = -Z4; zo[2] = -Z8;
    zo[3] = -Z1; zo[4] = -Z2; zo[5] = -Z5;
    zo[6] = Z0 + Z4 + Z8;
}

__device__ __forceinline__ void quat_to_mat(const float q[4], float R[9]) {
    float n = sqrtf(q[0]*q[0] + q[1]*q[1] + q[2]*q[2] + q[3]*q[3]);
    float w = q[0]/n, x = q[1]/n, y = q[2]/n, z = q[3]/n;
    R[0] = 1.f - 2.f*(y*y + z*z);
    R[1] = 2.f*(x*y - w*z);
    R[2] = 2.f*(x*z + w*y);
    R[3] = 2.f*(x*y + w*z);
    R[4] = 1.f - 2.f*(x*x + z*z);
    R[5] = 2.f*(y*z - w*x);
    R[6] = 2.f*(x*z - w*y);
    R[7] = 2.f*(y*z + w*x);
    R[8] = 1.f - 2.f*(x*x + y*y);
}

// Single-node fused kernel: partials + last-block finalize (device-global counter).
__global__ __launch_bounds__(TPB) void k_fused(
    const float* __restrict__ gt_quat,
    const float* __restrict__ mode_quat,
    const float* __restrict__ cov_tril,
    const float* __restrict__ grids,
    double* __restrict__ part,
    float* __restrict__ out, int n_total, int B)
{
    const int tile = blockIdx.x;
    const int bg   = blockIdx.y;
    const int tid  = threadIdx.x;

    __shared__ float zsh[BPB][8];
    __shared__ float gsh[CHUNK * 9];   // 9216 B raw rotation chunk
    __shared__ float red[TPB * 9];     // reduction scratch
    __shared__ int   last_flag;

    if (tid < BPB) {
        float zo[7];
        compute_Z_neg(cov_tril + (bg * BPB + tid) * 9, zo);
#pragma unroll
        for (int j = 0; j < 7; ++j) zsh[tid][j] = zo[j];
    }
    __syncthreads();

    float z[BPB][7];
#pragma unroll
    for (int bl = 0; bl < BPB; ++bl)
#pragma unroll
        for (int j = 0; j < 7; ++j) z[bl][j] = zsh[bl][j];

    float acc[BPB];
#pragma unroll
    for (int bl = 0; bl < BPB; ++bl) acc[bl] = 0.f;

    const float4* gsrc = (const float4*)grids + (size_t)tile * (NCHUNK * 9 / 4);

    for (int c = 0; c < NCHUNKS; ++c) {
        const float4* src = gsrc + c * (CHUNK * 9 / 4);
        float4 v0 = src[tid];
        float4 v1 = src[tid + 256];
        float4 v2;
        if (tid < 64) v2 = src[tid + 512];

        __syncthreads();
        ((float4*)gsh)[tid]       = v0;
        ((float4*)gsh)[tid + 256] = v1;
        if (tid < 64) ((float4*)gsh)[tid + 512] = v2;
        __syncthreads();

        const float* G = gsh + tid * 9;   // stride 9: conflict-free
        float G0=G[0],G1=G[1],G2=G[2],G3=G[3],G4=G[4],G5=G[5],G6=G[6],G7=G[7],G8=G[8];
        float g0 = G0, g1 = G4, g2 = G8;
        float g3 = G1 + G3, g4 = G2 + G6, g5 = G5 + G7;

#pragma unroll
        for (int bl = 0; bl < BPB; ++bl) {
            float x = z[bl][6];
            x = fmaf(z[bl][0], g0, x);
            x = fmaf(z[bl][1], g1, x);
            x = fmaf(z[bl][2], g2, x);
            x = fmaf(z[bl][3], g3, x);
            x = fmaf(z[bl][4], g4, x);
            x = fmaf(z[bl][5], g5, x);
            x = fmaxf(x, 1e-8f);
            float r = FAST_RSQ(x);            // 1/p
            float p = x * r;                  // sqrt(x)
            float e = FAST_EXP2(-LOG2E * p);  // exp(-p)
            acc[bl] = fmaf(e, r, acc[bl]);    // += exp(-p)/p
        }
    }

    // two-stage block reduce: [256 threads][8 b] -> 8 sums
#pragma unroll
    for (int bl = 0; bl < BPB; ++bl) red[tid * 9 + bl] = acc[bl];
    __syncthreads();

    const int bl = tid & 7;
    const int s  = tid >> 3;
    float p_ = 0.f;
#pragma unroll
    for (int j = 0; j < 8; ++j) p_ += red[(s * 8 + j) * 9 + bl];
    __syncthreads();
    red[tid] = p_;
    __syncthreads();

    if (tid < BPB) {
        double S = 0.0;
#pragma unroll
        for (int j = 0; j < 32; ++j) S += (double)red[j * 8 + tid];
        __hip_atomic_store(&part[(size_t)tile * B + bg * BPB + tid], S,
                           __ATOMIC_RELAXED, __HIP_MEMORY_SCOPE_AGENT);
    }
    __syncthreads();

    // completion count; last block finalizes (fixed-order sum -> deterministic)
    if (tid == 0) {
        __threadfence();   // release: my partials visible device-wide
        unsigned old = __hip_atomic_fetch_add(&g_cnt, 1u, __ATOMIC_ACQ_REL,
                                              __HIP_MEMORY_SCOPE_AGENT);
        last_flag = (old == NBLOCKS - 1);
        if (last_flag)     // all 768 increments done; restore 0 for next launch
            __hip_atomic_store(&g_cnt, 0u, __ATOMIC_RELAXED, __HIP_MEMORY_SCOPE_AGENT);
    }
    __syncthreads();

    if (last_flag) {
        __threadfence();   // acquire side: see all partials
        const int b = tid; // B == TPB == 256
        double S = 0.0;
#pragma unroll
        for (int t = 0; t < NTILES; ++t)
            S += __hip_atomic_load(&part[(size_t)t * B + b],
                                   __ATOMIC_RELAXED, __HIP_MEMORY_SCOPE_AGENT);

        float zo[7];
        compute_Z_neg(cov_tril + b * 9, zo);

        float q0[4] = {mode_quat[b*4+0], mode_quat[b*4+1], mode_quat[b*4+2], mode_quat[b*4+3]};
        float qg[4] = {gt_quat[b*4+0],   gt_quat[b*4+1],   gt_quat[b*4+2],   gt_quat[b*4+3]};
        float R0[9], Rg[9];
        quat_to_mat(q0, R0);
        quat_to_mat(qg, Rg);

        float Rr[9];
#pragma unroll
        for (int i = 0; i < 3; ++i)
#pragma unroll
            for (int j = 0; j < 3; ++j)
                Rr[i*3+j] = R0[0*3+i]*Rg[0*3+j] + R0[1*3+i]*Rg[1*3+j] + R0[2*3+i]*Rg[2*3+j];

        float x = zo[6];
        x = fmaf(zo[0], Rr[0], x);
        x = fmaf(zo[1], Rr[4], x);
        x = fmaf(zo[2], Rr[8], x);
        x = fmaf(zo[3], Rr[1] + Rr[3], x);
        x = fmaf(zo[4], Rr[2] + Rr[6], x);
        x = fmaf(zo[5], Rr[5] + Rr[7], x);

        float power = sqrtf(fmaxf(x, 1e-8f));
        float logF  = (float)(log(S) - log((double)n_total));
        out[b] = logF + power + logf(power);
    }
}

extern "C" void kernel_launch(void* const* d_in, const int* in_sizes, int n_in,
                              void* d_out, int out_size, void* d_ws, size_t ws_size,
                              hipStream_t stream) {
    const float* gt    = (const float*)d_in[0];
    const float* mode  = (const float*)d_in[1];
    const float* cov   = (const float*)d_in[2];
    const float* grids = (const float*)d_in[3];
    float* out = (float*)d_out;

    int B       = in_sizes[0] / 4;     // 256
    int n_total = in_sizes[3] / 9;     // 36864

    double* part = (double*)d_ws;      // 24*256 doubles = 48 KB

    dim3 grid(NTILES, BGRPS);          // 768 blocks
    k_fused<<<grid, TPB, 0, stream>>>(gt, mode, cov, grids, part, out, n_total, B);
}

// Round 9
// 16.435 us; speedup vs baseline: 3.8298x; 2.2223x over previous
//
#include <hip/hip_runtime.h>
#include <math.h>

#define TPB 256
#define BPB 8                    // batch elements per block
#define CHUNK 256                // rotations staged into LDS per pass
#define NCHUNKS 3                // chunks per block-tile
#define NCHUNK (CHUNK * NCHUNKS) // 768 rotations per block-tile
#define NTILES 48                // 48 * 768 = 36864
#define BGRPS 32                 // 256 / BPB
#define LOG2E 1.44269504088896340736f

#if __has_builtin(__builtin_amdgcn_rsqf)
#define FAST_RSQ(x) __builtin_amdgcn_rsqf(x)
#else
#define FAST_RSQ(x) rsqrtf(x)
#endif
#if __has_builtin(__builtin_amdgcn_exp2f)
#define FAST_EXP2(x) __builtin_amdgcn_exp2f(x)
#else
#define FAST_EXP2(x) exp2f(x)
#endif

// {-Z0,-Z4,-Z8,-Z1,-Z2,-Z5, trZ} for FMA-friendly x = trZ - tr(Z R)
__device__ __forceinline__ void compute_Z_neg(const float* __restrict__ L, float zo[7]) {
    float a = L[0], l10 = L[3], c = L[4], d = L[6], e = L[7], f = L[8];
    float ia = 1.0f / a, ic = 1.0f / c, iff = 1.0f / f;
    float m00 = ia;
    float m10 = -l10 * ia * ic;
    float m11 = ic;
    float m20 = (l10 * e - c * d) * ia * ic * iff;
    float m21 = -e * ic * iff;
    float m22 = iff;
    float Z0 = m00*m00 + m10*m10 + m20*m20;
    float Z1 = m10*m11 + m20*m21;
    float Z2 = m20*m22;
    float Z4 = m11*m11 + m21*m21;
    float Z5 = m21*m22;
    float Z8 = m22*m22;
    zo[0] = -Z0; zo[1] = -Z4; zo[2] = -Z8;
    zo[3] = -Z1; zo[4] = -Z2; zo[5] = -Z5;
    zo[6] = Z0 + Z4 + Z8;
}

__device__ __forceinline__ void quat_to_mat(const float q[4], float R[9]) {
    float n = sqrtf(q[0]*q[0] + q[1]*q[1] + q[2]*q[2] + q[3]*q[3]);
    float w = q[0]/n, x = q[1]/n, y = q[2]/n, z = q[3]/n;
    R[0] = 1.f - 2.f*(y*y + z*z);
    R[1] = 2.f*(x*y - w*z);
    R[2] = 2.f*(x*z + w*y);
    R[3] = 2.f*(x*y + w*z);
    R[4] = 1.f - 2.f*(x*x + z*z);
    R[5] = 2.f*(y*z - w*x);
    R[6] = 2.f*(x*z - w*y);
    R[7] = 2.f*(y*z + w*x);
    R[8] = 1.f - 2.f*(x*x + y*y);
}

// K1: grid (NTILES, BGRPS) = 1536 blocks (6/CU). LDS-staged coalesced loads,
// 8-b register inner loop. No cross-block sync (two-node graph is optimal: R5/R7/R8).
__global__ __launch_bounds__(TPB) void k_part(
    const float* __restrict__ cov_tril,
    const float* __restrict__ grids,
    double* __restrict__ part, int B)
{
    const int tile = blockIdx.x;
    const int bg   = blockIdx.y;
    const int tid  = threadIdx.x;

    __shared__ float zsh[BPB][8];
    __shared__ float gsh[CHUNK * 9];   // 9216 B raw rotation chunk
    __shared__ float red[TPB * 9];     // reduction scratch

    if (tid < BPB) {
        float zo[7];
        compute_Z_neg(cov_tril + (bg * BPB + tid) * 9, zo);
#pragma unroll
        for (int j = 0; j < 7; ++j) zsh[tid][j] = zo[j];
    }
    __syncthreads();

    float z[BPB][7];
#pragma unroll
    for (int bl = 0; bl < BPB; ++bl)
#pragma unroll
        for (int j = 0; j < 7; ++j) z[bl][j] = zsh[bl][j];

    float acc[BPB];
#pragma unroll
    for (int bl = 0; bl < BPB; ++bl) acc[bl] = 0.f;

    const float4* gsrc = (const float4*)grids + (size_t)tile * (NCHUNK * 9 / 4);

#pragma unroll
    for (int c = 0; c < NCHUNKS; ++c) {
        const float4* src = gsrc + c * (CHUNK * 9 / 4);
        float4 v0 = src[tid];
        float4 v1 = src[tid + 256];
        float4 v2;
        if (tid < 64) v2 = src[tid + 512];

        __syncthreads();
        ((float4*)gsh)[tid]       = v0;
        ((float4*)gsh)[tid + 256] = v1;
        if (tid < 64) ((float4*)gsh)[tid + 512] = v2;
        __syncthreads();

        const float* G = gsh + tid * 9;   // stride 9: conflict-free
        float G0=G[0],G1=G[1],G2=G[2],G3=G[3],G4=G[4],G5=G[5],G6=G[6],G7=G[7],G8=G[8];
        float g0 = G0, g1 = G4, g2 = G8;
        float g3 = G1 + G3, g4 = G2 + G6, g5 = G5 + G7;

#pragma unroll
        for (int bl = 0; bl < BPB; ++bl) {
            float x = z[bl][6];
            x = fmaf(z[bl][0], g0, x);
            x = fmaf(z[bl][1], g1, x);
            x = fmaf(z[bl][2], g2, x);
            x = fmaf(z[bl][3], g3, x);
            x = fmaf(z[bl][4], g4, x);
            x = fmaf(z[bl][5], g5, x);
            x = fmaxf(x, 1e-8f);
            float r = FAST_RSQ(x);            // 1/p
            float p = x * r;                  // sqrt(x)
            float e = FAST_EXP2(-LOG2E * p);  // exp(-p)
            acc[bl] = fmaf(e, r, acc[bl]);    // += exp(-p)/p
        }
    }

    // two-stage block reduce: [256 threads][8 b] -> 8 sums
#pragma unroll
    for (int bl = 0; bl < BPB; ++bl) red[tid * 9 + bl] = acc[bl];
    __syncthreads();

    const int bl = tid & 7;
    const int s  = tid >> 3;
    float p_ = 0.f;
#pragma unroll
    for (int j = 0; j < 8; ++j) p_ += red[(s * 8 + j) * 9 + bl];
    __syncthreads();
    red[tid] = p_;
    __syncthreads();

    if (tid < BPB) {
        double S = 0.0;
#pragma unroll
        for (int j = 0; j < 32; ++j) S += (double)red[j * 8 + tid];
        part[(size_t)tile * B + bg * BPB + tid] = S;
    }
}

// K2: finalize per b (1 block of 256; part reads coalesced across threads)
__global__ __launch_bounds__(TPB) void k_fin(
    const float* __restrict__ gt_quat,
    const float* __restrict__ mode_quat,
    const float* __restrict__ cov_tril,
    const double* __restrict__ part,
    float* __restrict__ out, int n_total, int B)
{
    const int b = threadIdx.x;   // B == TPB == 256

    double S = 0.0;
#pragma unroll
    for (int t = 0; t < NTILES; ++t) S += part[(size_t)t * B + b];

    float zo[7];
    compute_Z_neg(cov_tril + b * 9, zo);

    float q0[4] = {mode_quat[b*4+0], mode_quat[b*4+1], mode_quat[b*4+2], mode_quat[b*4+3]};
    float qg[4] = {gt_quat[b*4+0],   gt_quat[b*4+1],   gt_quat[b*4+2],   gt_quat[b*4+3]};
    float R0[9], Rg[9];
    quat_to_mat(q0, R0);
    quat_to_mat(qg, Rg);

    float Rr[9];
#pragma unroll
    for (int i = 0; i < 3; ++i)
#pragma unroll
        for (int j = 0; j < 3; ++j)
            Rr[i*3+j] = R0[0*3+i]*Rg[0*3+j] + R0[1*3+i]*Rg[1*3+j] + R0[2*3+i]*Rg[2*3+j];

    float x = zo[6];
    x = fmaf(zo[0], Rr[0], x);
    x = fmaf(zo[1], Rr[4], x);
    x = fmaf(zo[2], Rr[8], x);
    x = fmaf(zo[3], Rr[1] + Rr[3], x);
    x = fmaf(zo[4], Rr[2] + Rr[6], x);
    x = fmaf(zo[5], Rr[5] + Rr[7], x);

    float power = sqrtf(fmaxf(x, 1e-8f));
    float logF  = (float)(log(S) - log((double)n_total));
    out[b] = logF + power + logf(power);
}

extern "C" void kernel_launch(void* const* d_in, const int* in_sizes, int n_in,
                              void* d_out, int out_size, void* d_ws, size_t ws_size,
                              hipStream_t stream) {
    const float* gt    = (const float*)d_in[0];
    const float* mode  = (const float*)d_in[1];
    const float* cov   = (const float*)d_in[2];
    const float* grids = (const float*)d_in[3];
    float* out = (float*)d_out;

    int B       = in_sizes[0] / 4;     // 256
    int n_total = in_sizes[3] / 9;     // 36864

    double* part = (double*)d_ws;      // 48*256 doubles = 96 KB

    dim3 grid(NTILES, BGRPS);          // 1536 blocks = 6/CU
    k_part<<<grid, TPB, 0, stream>>>(cov, grids, part, B);
    k_fin<<<1, TPB, 0, stream>>>(gt, mode, cov, part, out, n_total, B);
}